// Round 12
// baseline (4327.937 us; speedup 1.0000x reference)
//
#include <hip/hip_runtime.h>

// RNN: B=64, T=512, I=1024, H=1024, fp32 in/out.
// Phase 0: transpose-convert Wx/Wh -> bf16 [N][K] in ws.
// Phase 1: xproj = x @ Wx + bx + bh (bf16 MFMA, fp32 accum) -> d_out.
// Phase 2: persistent MFMA scan, 32 blocks x 512 thr = 4 clusters x 8 members.
//   cluster c: 16 batches = 2 groups of 8; half-steps alternate groups.
//   Half-step(g,t): poll next group's per-wave flags -> issue its h-tile via
//   global_load_lds (sc0|sc1, source pre-swizzled) -> #A -> MFMA group g
//   (tile staged & drained last half-step) -> #P -> reduce -> tanh ->
//   publish sc0sc1 -> vmcnt(0) -> lane0 wave-flag. Stage RT hides under
//   compute; the only serial MALL RTs are poll (~1 iter) + publish-ack.
//   All drains are vmcnt(0) (no counting); no asm-load registers in flight
//   across source (R10 lesson); flag protocol gives skew a restoring force
//   (laggards never wait) unlike tagged-optimistic (R11 lesson).
//   Wh B-frags PINNED via whole-vector asm (R7..R11 had VGPR~100 < 128 =>
//   compiler was re-fetching Wh from L2 every step).

#define Bdim 64
#define Tdim 512
#define Idim 1024
#define Hdim 1024
#define Mdim (Bdim * Tdim)  // 32768

typedef __attribute__((ext_vector_type(8))) short bf16x8;
typedef __attribute__((ext_vector_type(4))) float f32x4;
typedef __attribute__((ext_vector_type(4))) unsigned int u32x4;

__device__ __forceinline__ float tanh_fast(float x) {
  float e = __expf(2.0f * x);
  return 1.0f - 2.0f / (e + 1.0f);
}
__device__ __forceinline__ unsigned int f2bf(float f) {
  unsigned int u = __float_as_uint(f);
  return (u + 0x7FFFu + ((u >> 16) & 1u)) >> 16;  // RNE
}
__device__ __forceinline__ unsigned int pack2(float lo, float hi) {
  return f2bf(lo) | (f2bf(hi) << 16);
}

// global -> LDS direct (16B/lane), L1-bypass + L2-bypass (sc0|sc1 = 0x11).
// LDS dest is wave-uniform base + lane*16 (m104); swizzle goes on the SOURCE.
typedef const __attribute__((address_space(1))) unsigned int* gas1_t;
typedef __attribute__((address_space(3))) unsigned int* las3_t;
__device__ __forceinline__ void gload_lds16(const void* g, void* l) {
  __builtin_amdgcn_global_load_lds((gas1_t)(unsigned long long)g,
                                   (las3_t)(unsigned int)(unsigned long long)l,
                                   16, 0, 0x11);
}

// ---------------- Phase 0: fp32 [K][N] -> bf16 transposed [N][K] -------------
__global__ __launch_bounds__(256) void cvt_transpose(
    const float* __restrict__ src, unsigned short* __restrict__ dst) {
  __shared__ float t[32][33];
  const int bx = blockIdx.x * 32;
  const int by = blockIdx.y * 32;
  const int ty = threadIdx.x >> 3;
  const int tx = threadIdx.x & 7;
  float4 v = *(const float4*)&src[(size_t)(by + ty) * 1024 + bx + tx * 4];
  t[ty][tx * 4 + 0] = v.x; t[ty][tx * 4 + 1] = v.y;
  t[ty][tx * 4 + 2] = v.z; t[ty][tx * 4 + 3] = v.w;
  __syncthreads();
  ushort4 o;
  o.x = (unsigned short)f2bf(t[tx * 4 + 0][ty]);
  o.y = (unsigned short)f2bf(t[tx * 4 + 1][ty]);
  o.z = (unsigned short)f2bf(t[tx * 4 + 2][ty]);
  o.w = (unsigned short)f2bf(t[tx * 4 + 3][ty]);
  *(ushort4*)&dst[(size_t)(bx + ty) * 1024 + by + tx * 4] = o;
}

// ---------------- Phase 1: bf16 MFMA GEMM, 128x128 tile, BK=32 ---------------
__global__ __launch_bounds__(256) void xg_mfma(
    const float* __restrict__ X,            // [M][K] fp32
    const unsigned short* __restrict__ WxT, // [N][K] bf16
    const float* __restrict__ bx, const float* __restrict__ bh,
    float* __restrict__ C) {                // [M][N] fp32
  __shared__ char sAB[16384] __attribute__((aligned(16)));
  char* sA = sAB;
  char* sB = sAB + 8192;
  const int tid = threadIdx.x;
  const int m0 = blockIdx.y * 128;
  const int n0 = blockIdx.x * 128;
  const int w = tid >> 6, l = tid & 63;
  const int wm = (w >> 1) * 64, wn = (w & 1) * 64;
  const int r2 = tid >> 1, kh = tid & 1;

  f32x4 acc[4][4];
#pragma unroll
  for (int i = 0; i < 4; ++i)
#pragma unroll
    for (int j = 0; j < 4; ++j) acc[i][j] = (f32x4){0.f, 0.f, 0.f, 0.f};

  for (int k0 = 0; k0 < Idim; k0 += 32) {
    const float* xa = &X[(size_t)(m0 + r2) * Idim + k0 + kh * 16];
    float4 a0 = *(const float4*)(xa + 0), a1 = *(const float4*)(xa + 4);
    float4 a2 = *(const float4*)(xa + 8), a3 = *(const float4*)(xa + 12);
    const char* wb = (const char*)&WxT[(size_t)(n0 + r2) * Idim + k0 + kh * 16];
    u32x4 b0 = *(const u32x4*)wb;
    u32x4 b1 = *(const u32x4*)(wb + 16);
    __syncthreads();
    u32x4 pa0 = {pack2(a0.x, a0.y), pack2(a0.z, a0.w),
                 pack2(a1.x, a1.y), pack2(a1.z, a1.w)};
    u32x4 pa1 = {pack2(a2.x, a2.y), pack2(a2.z, a2.w),
                 pack2(a3.x, a3.y), pack2(a3.z, a3.w)};
    const int sw = (r2 & 7) << 4;
    const int rb = r2 * 64 + kh * 32;
    *(u32x4*)(sA + ((rb + 0) ^ sw)) = pa0;
    *(u32x4*)(sA + ((rb + 16) ^ sw)) = pa1;
    *(u32x4*)(sB + ((rb + 0) ^ sw)) = b0;
    *(u32x4*)(sB + ((rb + 16) ^ sw)) = b1;
    __syncthreads();
    bf16x8 af[4], bf[4];
#pragma unroll
    for (int i = 0; i < 4; ++i) {
      int ra = wm + i * 16 + (l & 15);
      af[i] = *(const bf16x8*)(sA + ((ra * 64 + (l >> 4) * 16) ^ ((ra & 7) << 4)));
      int rn = wn + i * 16 + (l & 15);
      bf[i] = *(const bf16x8*)(sB + ((rn * 64 + (l >> 4) * 16) ^ ((rn & 7) << 4)));
    }
#pragma unroll
    for (int i = 0; i < 4; ++i)
#pragma unroll
      for (int j = 0; j < 4; ++j)
        acc[i][j] = __builtin_amdgcn_mfma_f32_16x16x32_bf16(af[i], bf[j],
                                                            acc[i][j], 0, 0, 0);
  }
  float bias[4];
#pragma unroll
  for (int j = 0; j < 4; ++j) {
    int cc = n0 + wn + j * 16 + (l & 15);
    bias[j] = bx[cc] + bh[cc];
  }
#pragma unroll
  for (int i = 0; i < 4; ++i) {
    int rbase = m0 + wm + i * 16 + (l >> 4) * 4;
#pragma unroll
    for (int j = 0; j < 4; ++j) {
      int cc = n0 + wn + j * 16 + (l & 15);
#pragma unroll
      for (int r = 0; r < 4; ++r)
        C[(size_t)(rbase + r) * Hdim + cc] = acc[i][j][r] + bias[j];
    }
  }
}

// ---------------- flag clear (agent stores -> MALL) --------------------------
__global__ void clear_flags(unsigned int* flags) {
  __hip_atomic_store(&flags[threadIdx.x], 0u, __ATOMIC_RELAXED,
                     __HIP_MEMORY_SCOPE_AGENT);
}

// ---------------- Phase 2: persistent MFMA scan, pipelined half-steps --------
// flags: [(c*2+g)*64 + m*8 + w], 512 dwords.
// hbuf payload regions: ((c<<2)|(g<<1)|par) * 16 KB; row w = 2 KB; dword
// index within region = w*512 + m*64 + l.
__global__ __launch_bounds__(512, 2) void rnn_scan(
    const unsigned short* __restrict__ WhT,  // [N=1024][K=1024] bf16
    float* __restrict__ out,                 // [B][T][H]: xproj in, h out
    float* __restrict__ hlast,               // [B][H]
    unsigned int* hbuf,                      // ws: 256 KB payload
    unsigned int* flags) {                   // ws: 512 dwords
  const int bid = blockIdx.x;
  const int c = bid & 3;   // cluster: batches c*16..+16
  const int m = bid >> 2;  // member: cols m*128..+128
  const int tid = threadIdx.x;
  const int w = tid >> 6;  // wave: k-slice w*128..+128; finisher batch row w
  const int l = tid & 63;
  const int n0 = m * 128;

  __shared__ char smem[16384 + 16384 + 33792] __attribute__((aligned(16)));
  char* const smh0 = smem;           // group0 h tile [8][2048B], swizzled
  char* const smh1 = smem + 16384;   // group1 h tile
  char* const smp = smem + 32768;    // partials [8w][8nt][33][16B]

  // B-frags: Wh[k=w*128..+128][cols n0..+128] = 32 x bf16x8 = 128 VGPR/lane.
  bf16x8 bfrag[32];
  {
    const int kb = (w << 7) + ((l >> 4) << 3);
    const int col = n0 + (l & 15);
#pragma unroll
    for (int nt = 0; nt < 8; ++nt)
#pragma unroll
      for (int kt = 0; kt < 4; ++kt)
        bfrag[nt * 4 + kt] =
            *(const bf16x8*)&WhT[(size_t)(col + nt * 16) * 1024 + kb + kt * 32];
  }
  // PIN: whole-vector asm per element keeps all 128 VGPRs resident (no
  // rematerialized L2 re-fetch inside the loop).
#pragma unroll
  for (int i = 0; i < 32; ++i) asm volatile("" : "+v"(bfrag[i]));

  const int c0 = l * 2;  // col pair this thread finishes
  const int nt0 = c0 >> 4;
  const int lane0 = ((w >> 2) << 4) | (c0 & 15);
  const int regb = (w & 3) * 4;
  const size_t obase0 =
      (size_t)(c * 16 + 0 + w) * ((size_t)Tdim * Hdim) + n0 + c0;
  const size_t obase1 =
      (size_t)(c * 16 + 8 + w) * ((size_t)Tdim * Hdim) + n0 + c0;
  float2 xp0 = *(const float2*)&out[obase0];
  float2 xp1 = *(const float2*)&out[obase1];

  auto half = [&](const int g, const int t, float2& xp, const size_t obase,
                  char* const smhg, char* const smhn) __attribute__((always_inline)) {
    const int gg = g ^ 1;
    const int tn = (g == 0) ? t : t + 1;  // tile time for NEXT half-step (gg)
    if (tn >= 1 && tn <= 511) {
      // ---- poll next group's 64 per-wave flags (one line; throttled) ----
      const unsigned int* fp = &flags[((c << 1) | gg) * 64 + l];
      const unsigned int tgt = (unsigned int)tn;
      for (;;) {
        unsigned int v;
        asm volatile("global_load_dword %0, %1, off sc0 sc1\n\ts_waitcnt vmcnt(0)"
                     : "=v"(v) : "v"(fp) : "memory");
        if (__ballot(v >= tgt) == ~0ull) break;
        __builtin_amdgcn_s_sleep(1);
      }
      __builtin_amdgcn_sched_barrier(0);
      // ---- issue next tile: wave w stages batch row w (2 KB) ----
      const char* rgn = (const char*)hbuf +
                        (size_t)((c << 2) | (gg << 1) | (tn & 1)) * 16384;
      const char* s0 = rgn + w * 2048 + ((l * 16) ^ (w << 4));
      const char* s1 = rgn + w * 2048 + ((1024 + l * 16) ^ (w << 4));
      gload_lds16(s0, smhn + w * 2048);
      gload_lds16(s1, smhn + w * 2048 + 1024);
    }
    __builtin_amdgcn_s_barrier();  // #A: this half's tile staged by all waves
    asm volatile("" ::: "memory");
    float sum0 = 0.f, sum1 = 0.f;
    if (t > 0) {
      const int arow = l & 7;
      const int ab = arow * 2048 + (w << 8) + ((l >> 4) << 4);
      const int sw2 = arow << 4;
      bf16x8 af0 = *(const bf16x8*)(smhg + ((ab + 0) ^ sw2));
      bf16x8 af1 = *(const bf16x8*)(smhg + ((ab + 64) ^ sw2));
      bf16x8 af2 = *(const bf16x8*)(smhg + ((ab + 128) ^ sw2));
      bf16x8 af3 = *(const bf16x8*)(smhg + ((ab + 192) ^ sw2));
#pragma unroll
      for (int nt = 0; nt < 8; ++nt) {
        f32x4 a = {0.f, 0.f, 0.f, 0.f};
        a = __builtin_amdgcn_mfma_f32_16x16x32_bf16(af0, bfrag[nt * 4 + 0], a, 0, 0, 0);
        a = __builtin_amdgcn_mfma_f32_16x16x32_bf16(af1, bfrag[nt * 4 + 1], a, 0, 0, 0);
        a = __builtin_amdgcn_mfma_f32_16x16x32_bf16(af2, bfrag[nt * 4 + 2], a, 0, 0, 0);
        a = __builtin_amdgcn_mfma_f32_16x16x32_bf16(af3, bfrag[nt * 4 + 3], a, 0, 0, 0);
        if (l < 32)  // lanes 32-63 hold duplicate batch rows: discard
          *(f32x4*)(smp + (((w * 8 + nt) * 33 + l) << 4)) = a;
      }
      asm volatile("s_waitcnt lgkmcnt(0)" ::: "memory");
      __builtin_amdgcn_s_barrier();  // #P: partials visible
      asm volatile("" ::: "memory");
#pragma unroll
      for (int w8 = 0; w8 < 8; ++w8) {
        const char* p = smp + (((w8 * 8 + nt0) * 33 + lane0) << 4) + regb;
        sum0 += *(const float*)p;
        sum1 += *(const float*)(p + 16);
      }
    }
    float h0 = tanh_fast(xp.x + sum0);
    float h1 = tanh_fast(xp.y + sum1);
    if (t < Tdim - 1) {
      // publish -> drain (also drains this half's tile issues) -> wave flag
      unsigned int* pubp = hbuf +
                           (size_t)((c << 2) | (g << 1) | ((t + 1) & 1)) * 4096 +
                           w * 512 + m * 64 + l;
      unsigned int pv = pack2(h0, h1);
      asm volatile("global_store_dword %0, %1, off sc0 sc1"
                   :: "v"(pubp), "v"(pv) : "memory");
      asm volatile("s_waitcnt vmcnt(0)" ::: "memory");
      if (l == 0) {
        unsigned int* fl = &flags[((c << 1) | g) * 64 + m * 8 + w];
        unsigned int tv = (unsigned int)(t + 1);
        asm volatile("global_store_dword %0, %1, off sc0 sc1"
                     :: "v"(fl), "v"(tv) : "memory");
      }
      *(float2*)&out[obase + (size_t)t * Hdim] = make_float2(h0, h1);
      xp = *(const float2*)&out[obase + (size_t)(t + 1) * Hdim];
    } else {
      *(float2*)&out[obase + (size_t)t * Hdim] = make_float2(h0, h1);
      *(float2*)&hlast[(size_t)(c * 16 + g * 8 + w) * Hdim + n0 + c0] =
          make_float2(h0, h1);
      // drain any tile issues made this half-step (no publish path ran)
      asm volatile("s_waitcnt vmcnt(0)" ::: "memory");
    }
  };

  for (int t = 0; t < Tdim; ++t) {
    half(0, t, xp0, obase0, smh0, smh1);
    half(1, t, xp1, obase1, smh1, smh0);
  }
}

extern "C" void kernel_launch(void* const* d_in, const int* in_sizes, int n_in,
                              void* d_out, int out_size, void* d_ws,
                              size_t ws_size, hipStream_t stream) {
  const float* x  = (const float*)d_in[0];
  const float* Wx = (const float*)d_in[1];
  const float* bx = (const float*)d_in[2];
  const float* Wh = (const float*)d_in[3];
  const float* bh = (const float*)d_in[4];
  float* out = (float*)d_out;
  float* hlast = out + (size_t)Bdim * Tdim * Hdim;
  unsigned int* flags = (unsigned int*)d_ws;                       // 2 KB
  unsigned int* hbuf = (unsigned int*)((char*)d_ws + 4096);        // 256 KB
  unsigned short* WxT = (unsigned short*)((char*)d_ws + 4096 + 262144);
  unsigned short* WhT = (unsigned short*)((char*)d_ws + 4096 + 262144 + 2097152);

  clear_flags<<<1, dim3(512), 0, stream>>>(flags);
  dim3 gt(32, 32);
  cvt_transpose<<<gt, dim3(256), 0, stream>>>(Wx, WxT);
  cvt_transpose<<<gt, dim3(256), 0, stream>>>(Wh, WhT);
  xg_mfma<<<dim3(Hdim / 128, Mdim / 128), dim3(256), 0, stream>>>(x, WxT, bx,
                                                                  bh, out);
  rnn_scan<<<dim3(32), dim3(512), 0, stream>>>(WhT, out, hlast, hbuf, flags);
}

// Round 13
// 2224.244 us; speedup vs baseline: 1.9458x; 1.9458x over previous
//
#include <hip/hip_runtime.h>

// RNN: B=64, T=512, I=1024, H=1024, fp32 in/out.
// Phase 0: transpose-convert Wx/Wh -> bf16 [N][K] in ws.
// Phase 1: xproj = x @ Wx + bx + bh (bf16 MFMA, fp32 accum) -> d_out.
// Phase 2: persistent MFMA scan, 64 blocks x 512 thr = 8 clusters x 8 members
//   (R7-proven geometry: cluster c batches c*8..+8, member m cols m*128..+128,
//   wave w k-slice w*128 and batch-row w).
//   Protocol surgery vs R7 (each RT overlapped or de-barriered):
//   - publish + out-store in ONE asm w/ vmcnt(0): latencies overlap.
//   - per-wave flag after the wave's own drain (vmcnt is per-wave) -> no #B.
//   - wave7 poll: first vmcnt(0) also drains the flag store (overlap); sleep(1).
//   - stage asm also prefetches xp@t+2, drained IN-statement (R10 rule:
//     no asm-load register in flight across source).
//   3 barriers/step (#P partials, #C flags-observed, #D tile-staged).

#define Bdim 64
#define Tdim 512
#define Idim 1024
#define Hdim 1024
#define Mdim (Bdim * Tdim)  // 32768

typedef __attribute__((ext_vector_type(8))) short bf16x8;
typedef __attribute__((ext_vector_type(4))) float f32x4;
typedef __attribute__((ext_vector_type(2))) float f32x2;
typedef __attribute__((ext_vector_type(4))) unsigned int u32x4;

__device__ __forceinline__ float tanh_fast(float x) {
  float e = __expf(2.0f * x);
  return 1.0f - 2.0f / (e + 1.0f);
}
__device__ __forceinline__ unsigned int f2bf(float f) {
  unsigned int u = __float_as_uint(f);
  return (u + 0x7FFFu + ((u >> 16) & 1u)) >> 16;  // RNE
}
__device__ __forceinline__ unsigned int pack2(float lo, float hi) {
  return f2bf(lo) | (f2bf(hi) << 16);
}

// ---------------- Phase 0: fp32 [K][N] -> bf16 transposed [N][K] -------------
__global__ __launch_bounds__(256) void cvt_transpose(
    const float* __restrict__ src, unsigned short* __restrict__ dst) {
  __shared__ float t[32][33];
  const int bx = blockIdx.x * 32;
  const int by = blockIdx.y * 32;
  const int ty = threadIdx.x >> 3;
  const int tx = threadIdx.x & 7;
  float4 v = *(const float4*)&src[(size_t)(by + ty) * 1024 + bx + tx * 4];
  t[ty][tx * 4 + 0] = v.x; t[ty][tx * 4 + 1] = v.y;
  t[ty][tx * 4 + 2] = v.z; t[ty][tx * 4 + 3] = v.w;
  __syncthreads();
  ushort4 o;
  o.x = (unsigned short)f2bf(t[tx * 4 + 0][ty]);
  o.y = (unsigned short)f2bf(t[tx * 4 + 1][ty]);
  o.z = (unsigned short)f2bf(t[tx * 4 + 2][ty]);
  o.w = (unsigned short)f2bf(t[tx * 4 + 3][ty]);
  *(ushort4*)&dst[(size_t)(bx + ty) * 1024 + by + tx * 4] = o;
}

// ---------------- Phase 1: bf16 MFMA GEMM, 128x128 tile, BK=32 ---------------
__global__ __launch_bounds__(256) void xg_mfma(
    const float* __restrict__ X,            // [M][K] fp32
    const unsigned short* __restrict__ WxT, // [N][K] bf16
    const float* __restrict__ bx, const float* __restrict__ bh,
    float* __restrict__ C) {                // [M][N] fp32
  __shared__ char sAB[16384] __attribute__((aligned(16)));
  char* sA = sAB;
  char* sB = sAB + 8192;
  const int tid = threadIdx.x;
  const int m0 = blockIdx.y * 128;
  const int n0 = blockIdx.x * 128;
  const int w = tid >> 6, l = tid & 63;
  const int wm = (w >> 1) * 64, wn = (w & 1) * 64;
  const int r2 = tid >> 1, kh = tid & 1;

  f32x4 acc[4][4];
#pragma unroll
  for (int i = 0; i < 4; ++i)
#pragma unroll
    for (int j = 0; j < 4; ++j) acc[i][j] = (f32x4){0.f, 0.f, 0.f, 0.f};

  for (int k0 = 0; k0 < Idim; k0 += 32) {
    const float* xa = &X[(size_t)(m0 + r2) * Idim + k0 + kh * 16];
    float4 a0 = *(const float4*)(xa + 0), a1 = *(const float4*)(xa + 4);
    float4 a2 = *(const float4*)(xa + 8), a3 = *(const float4*)(xa + 12);
    const char* wb = (const char*)&WxT[(size_t)(n0 + r2) * Idim + k0 + kh * 16];
    u32x4 b0 = *(const u32x4*)wb;
    u32x4 b1 = *(const u32x4*)(wb + 16);
    __syncthreads();
    u32x4 pa0 = {pack2(a0.x, a0.y), pack2(a0.z, a0.w),
                 pack2(a1.x, a1.y), pack2(a1.z, a1.w)};
    u32x4 pa1 = {pack2(a2.x, a2.y), pack2(a2.z, a2.w),
                 pack2(a3.x, a3.y), pack2(a3.z, a3.w)};
    const int sw = (r2 & 7) << 4;
    const int rb = r2 * 64 + kh * 32;
    *(u32x4*)(sA + ((rb + 0) ^ sw)) = pa0;
    *(u32x4*)(sA + ((rb + 16) ^ sw)) = pa1;
    *(u32x4*)(sB + ((rb + 0) ^ sw)) = b0;
    *(u32x4*)(sB + ((rb + 16) ^ sw)) = b1;
    __syncthreads();
    bf16x8 af[4], bf[4];
#pragma unroll
    for (int i = 0; i < 4; ++i) {
      int ra = wm + i * 16 + (l & 15);
      af[i] = *(const bf16x8*)(sA + ((ra * 64 + (l >> 4) * 16) ^ ((ra & 7) << 4)));
      int rn = wn + i * 16 + (l & 15);
      bf[i] = *(const bf16x8*)(sB + ((rn * 64 + (l >> 4) * 16) ^ ((rn & 7) << 4)));
    }
#pragma unroll
    for (int i = 0; i < 4; ++i)
#pragma unroll
      for (int j = 0; j < 4; ++j)
        acc[i][j] = __builtin_amdgcn_mfma_f32_16x16x32_bf16(af[i], bf[j],
                                                            acc[i][j], 0, 0, 0);
  }
  float bias[4];
#pragma unroll
  for (int j = 0; j < 4; ++j) {
    int cc = n0 + wn + j * 16 + (l & 15);
    bias[j] = bx[cc] + bh[cc];
  }
#pragma unroll
  for (int i = 0; i < 4; ++i) {
    int rbase = m0 + wm + i * 16 + (l >> 4) * 4;
#pragma unroll
    for (int j = 0; j < 4; ++j) {
      int cc = n0 + wn + j * 16 + (l & 15);
#pragma unroll
      for (int r = 0; r < 4; ++r)
        C[(size_t)(rbase + r) * Hdim + cc] = acc[i][j][r] + bias[j];
    }
  }
}

// ---------------- flag clear (agent stores -> MALL) --------------------------
__global__ void clear_flags(unsigned int* flags) {
  __hip_atomic_store(&flags[threadIdx.x], 0u, __ATOMIC_RELAXED,
                     __HIP_MEMORY_SCOPE_AGENT);
}

// ---------------- Phase 2: persistent MFMA scan ------------------------------
// flags: [c*64 + m*8 + w], 512 dwords. hbuf: [2 par][64 b][512 cp] dwords.
__global__ __launch_bounds__(512, 2) void rnn_scan(
    const unsigned short* __restrict__ WhT,  // [N=1024][K=1024] bf16
    float* __restrict__ out,                 // [B][T][H]: xproj in, h out
    float* __restrict__ hlast,               // [B][H]
    unsigned int* hbuf,                      // ws: 256 KB payload
    unsigned int* flags) {                   // ws: 512 dwords
  const int bid = blockIdx.x;
  const int c = bid & 7;   // cluster: batches c*8..+8
  const int m = bid >> 3;  // member: cols m*128..+128
  const int tid = threadIdx.x;
  const int w = tid >> 6;  // wave: k-slice w*128..+128; batch row w
  const int l = tid & 63;
  const int n0 = m * 128;

  __shared__ char smem[16384 + 33792] __attribute__((aligned(16)));
  char* const smh = smem;          // h tile [8 b][2048 B], XOR-swizzled
  char* const smp = smem + 16384;  // partials [8 w][8 nt][33][16 B]

  // B-frags: Wh[k=w*128..+128][cols n0..+128] = 32 x bf16x8 (VGPR/AGPR file)
  bf16x8 bfrag[32];
  {
    const int kb = (w << 7) + ((l >> 4) << 3);
    const int col = n0 + (l & 15);
#pragma unroll
    for (int nt = 0; nt < 8; ++nt)
#pragma unroll
      for (int kt = 0; kt < 4; ++kt)
        bfrag[nt * 4 + kt] =
            *(const bf16x8*)&WhT[(size_t)(col + nt * 16) * 1024 + kb + kt * 32];
  }
#pragma unroll
  for (int i = 0; i < 32; ++i) asm volatile("" : "+v"(bfrag[i]));

  const int c0 = l * 2;  // col pair this thread finishes
  const int b_abs = c * 8 + w;
  const int nt0 = c0 >> 4;
  const int lane0 = ((w >> 2) << 4) | (c0 & 15);
  const int regb = (w & 3) * 4;
  const size_t orow = (size_t)b_abs * ((size_t)Tdim * Hdim) + n0 + c0;
  unsigned int* const myflag = &flags[c * 64 + m * 8 + w];
  const unsigned int* const pollf = &flags[c * 64 + l];

  // xp pipeline, 2-deep: xpA = xp@t(even), xpB = xp@t(odd)
  f32x2 xpA, xpB;
  xpA[0] = out[orow];     xpA[1] = out[orow + 1];
  xpB[0] = out[orow + Hdim]; xpB[1] = out[orow + Hdim + 1];

  auto iter = [&](const int t, f32x2& xpu) __attribute__((always_inline)) {
    float sum0 = 0.f, sum1 = 0.f;
    if (t > 0) {
      // ---- compute from smh (staged last iteration) ----
      const int arow = l & 7;
      const int ab = arow * 2048 + (w << 8) + ((l >> 4) << 4);
      const int sw2 = arow << 4;
      bf16x8 af0 = *(const bf16x8*)(smh + ((ab + 0) ^ sw2));
      bf16x8 af1 = *(const bf16x8*)(smh + ((ab + 64) ^ sw2));
      bf16x8 af2 = *(const bf16x8*)(smh + ((ab + 128) ^ sw2));
      bf16x8 af3 = *(const bf16x8*)(smh + ((ab + 192) ^ sw2));
#pragma unroll
      for (int nt = 0; nt < 8; ++nt) {
        f32x4 a = {0.f, 0.f, 0.f, 0.f};
        a = __builtin_amdgcn_mfma_f32_16x16x32_bf16(af0, bfrag[nt * 4 + 0], a, 0, 0, 0);
        a = __builtin_amdgcn_mfma_f32_16x16x32_bf16(af1, bfrag[nt * 4 + 1], a, 0, 0, 0);
        a = __builtin_amdgcn_mfma_f32_16x16x32_bf16(af2, bfrag[nt * 4 + 2], a, 0, 0, 0);
        a = __builtin_amdgcn_mfma_f32_16x16x32_bf16(af3, bfrag[nt * 4 + 3], a, 0, 0, 0);
        if (l < 32)  // lanes 32-63 hold duplicate batch rows: discard
          *(f32x4*)(smp + (((w * 8 + nt) * 33 + l) << 4)) = a;
      }
      asm volatile("s_waitcnt lgkmcnt(0)" ::: "memory");
      __builtin_amdgcn_s_barrier();  // #P: partials visible
      asm volatile("" ::: "memory");
#pragma unroll
      for (int w8 = 0; w8 < 8; ++w8) {
        const char* p = smp + (((w8 * 8 + nt0) * 33 + lane0) << 4) + regb;
        sum0 += *(const float*)p;
        sum1 += *(const float*)(p + 16);
      }
    }
    float h0 = tanh_fast(xpu[0] + sum0);
    float h1 = tanh_fast(xpu[1] + sum1);
    if (t == Tdim - 1) {
      *(float2*)&out[orow + (size_t)t * Hdim] = make_float2(h0, h1);
      *(float2*)&hlast[(size_t)b_abs * Hdim + n0 + c0] = make_float2(h0, h1);
      return;
    }
    const int par = (t + 1) & 1;
    // ---- head: publish + out-store, one asm, one drain (overlapped) ----
    {
      unsigned int* pubp = hbuf + (size_t)par * 32768 + (size_t)b_abs * 512 +
                           m * 64 + l;
      unsigned int pv = pack2(h0, h1);
      f32x2 hh; hh[0] = h0; hh[1] = h1;
      float* op = &out[orow + (size_t)t * Hdim];
      asm volatile(
          "global_store_dword %0, %1, off sc0 sc1\n\t"
          "global_store_dwordx2 %2, %3, off nt\n\t"
          "s_waitcnt vmcnt(0)"
          :: "v"(pubp), "v"(pv), "v"(op), "v"(hh) : "memory");
    }
    // ---- per-wave flag (wave's own publishes proven drained) ----
    if (l == 0) {
      unsigned int tv = (unsigned int)(t + 1);
      asm volatile("global_store_dword %0, %1, off sc0 sc1"
                   :: "v"(myflag), "v"(tv) : "memory");
    }
    // ---- wave7 polls all 64 per-wave flags (flag-RT overlaps poll-RT) ----
    if (w == 7) {
      const unsigned int tgt = (unsigned int)(t + 1);
      for (;;) {
        unsigned int v;
        asm volatile(
            "global_load_dword %0, %1, off sc0 sc1\n\ts_waitcnt vmcnt(0)"
            : "=v"(v) : "v"(pollf) : "memory");
        if (__ballot(v >= tgt) == ~0ull) break;
        __builtin_amdgcn_s_sleep(1);
      }
    }
    __builtin_amdgcn_s_barrier();  // #C: flags observed
    asm volatile("" ::: "memory");
    // ---- stage tile for t+1 + prefetch xp@t+2, one asm, self-drained ----
    {
      const char* srcp = (const char*)hbuf + (size_t)par * 131072 +
                         (size_t)b_abs * 2048 + l * 32;
      const int t2 = (t + 2 > Tdim - 1) ? (Tdim - 1) : (t + 2);
      const float* xpp = &out[orow + (size_t)t2 * Hdim];
      u32x4 d0, d1;
      asm volatile(
          "global_load_dwordx4 %0, %3, off sc0 sc1\n\t"
          "global_load_dwordx4 %1, %3, off offset:16 sc0 sc1\n\t"
          "global_load_dwordx2 %2, %4, off\n\t"
          "s_waitcnt vmcnt(0)"
          : "=&v"(d0), "=&v"(d1), "=&v"(xpu)
          : "v"(srcp), "v"(xpp) : "memory");
      __builtin_amdgcn_sched_barrier(0);
      const int base = w * 2048 + l * 32;
      const int swz = w << 4;
      *(u32x4*)(smh + (base ^ swz)) = d0;
      *(u32x4*)(smh + ((base + 16) ^ swz)) = d1;
    }
    asm volatile("s_waitcnt lgkmcnt(0)" ::: "memory");
    __builtin_amdgcn_s_barrier();  // #D: tile staged
    asm volatile("" ::: "memory");
  };

  for (int tt = 0; tt < Tdim / 2; ++tt) {
    iter(2 * tt, xpA);      // consumes xp@2tt, refills xpA <- xp@2tt+2
    iter(2 * tt + 1, xpB);  // consumes xp@2tt+1, refills xpB <- xp@2tt+3
  }
}

extern "C" void kernel_launch(void* const* d_in, const int* in_sizes, int n_in,
                              void* d_out, int out_size, void* d_ws,
                              size_t ws_size, hipStream_t stream) {
  const float* x  = (const float*)d_in[0];
  const float* Wx = (const float*)d_in[1];
  const float* bx = (const float*)d_in[2];
  const float* Wh = (const float*)d_in[3];
  const float* bh = (const float*)d_in[4];
  float* out = (float*)d_out;
  float* hlast = out + (size_t)Bdim * Tdim * Hdim;
  unsigned int* flags = (unsigned int*)d_ws;                       // 2 KB
  unsigned int* hbuf = (unsigned int*)((char*)d_ws + 4096);        // 256 KB
  unsigned short* WxT = (unsigned short*)((char*)d_ws + 4096 + 262144);
  unsigned short* WhT = (unsigned short*)((char*)d_ws + 4096 + 262144 + 2097152);

  clear_flags<<<1, dim3(512), 0, stream>>>(flags);
  dim3 gt(32, 32);
  cvt_transpose<<<gt, dim3(256), 0, stream>>>(Wx, WxT);
  cvt_transpose<<<gt, dim3(256), 0, stream>>>(Wh, WhT);
  xg_mfma<<<dim3(Hdim / 128, Mdim / 128), dim3(256), 0, stream>>>(x, WxT, bx,
                                                                  bh, out);
  rnn_scan<<<dim3(64), dim3(512), 0, stream>>>(WhT, out, hlast, hbuf, flags);
}

// Round 14
// 1888.320 us; speedup vs baseline: 2.2920x; 1.1779x over previous
//
#include <hip/hip_runtime.h>

// RNN: B=64, T=512, I=1024, H=1024, fp32 in/out.
// Phase 0: transpose-convert Wx/Wh -> bf16 [N][K] in ws.
// Phase 1: xproj = x @ Wx + bx + bh (bf16 MFMA, fp32 accum) -> d_out.
// Phase 2: persistent MFMA scan, 64 blocks x 512 thr = 8 clusters x 8 members
//   (R7-proven geometry). R7 protocol with exactly three surgical deltas:
//   1) per-wave flag after the wave's OWN publish drain (vmcnt is per-wave)
//      -> #B barrier deleted. Poll of 64 wave-flags = same visibility proof.
//   2) out-store + xp-load are IR, issued AFTER the flag -> float across
//      poll/stage (R13 lesson: never put HBM ops inside a MALL drain).
//   3) wave7 poll, s_sleep(1).
//   Barriers/step: #C (flags observed), #D (tile staged), #P (partials).

#define Bdim 64
#define Tdim 512
#define Idim 1024
#define Hdim 1024
#define Mdim (Bdim * Tdim)  // 32768

typedef __attribute__((ext_vector_type(8))) short bf16x8;
typedef __attribute__((ext_vector_type(4))) float f32x4;
typedef __attribute__((ext_vector_type(4))) unsigned int u32x4;

__device__ __forceinline__ float tanh_fast(float x) {
  float e = __expf(2.0f * x);
  return 1.0f - 2.0f / (e + 1.0f);
}
__device__ __forceinline__ unsigned int f2bf(float f) {
  unsigned int u = __float_as_uint(f);
  return (u + 0x7FFFu + ((u >> 16) & 1u)) >> 16;  // RNE
}
__device__ __forceinline__ unsigned int pack2(float lo, float hi) {
  return f2bf(lo) | (f2bf(hi) << 16);
}

// ---------------- Phase 0: fp32 [K][N] -> bf16 transposed [N][K] -------------
__global__ __launch_bounds__(256) void cvt_transpose(
    const float* __restrict__ src, unsigned short* __restrict__ dst) {
  __shared__ float t[32][33];
  const int bx = blockIdx.x * 32;
  const int by = blockIdx.y * 32;
  const int ty = threadIdx.x >> 3;
  const int tx = threadIdx.x & 7;
  float4 v = *(const float4*)&src[(size_t)(by + ty) * 1024 + bx + tx * 4];
  t[ty][tx * 4 + 0] = v.x; t[ty][tx * 4 + 1] = v.y;
  t[ty][tx * 4 + 2] = v.z; t[ty][tx * 4 + 3] = v.w;
  __syncthreads();
  ushort4 o;
  o.x = (unsigned short)f2bf(t[tx * 4 + 0][ty]);
  o.y = (unsigned short)f2bf(t[tx * 4 + 1][ty]);
  o.z = (unsigned short)f2bf(t[tx * 4 + 2][ty]);
  o.w = (unsigned short)f2bf(t[tx * 4 + 3][ty]);
  *(ushort4*)&dst[(size_t)(bx + ty) * 1024 + by + tx * 4] = o;
}

// ---------------- Phase 1: bf16 MFMA GEMM, 128x128 tile, BK=32 ---------------
__global__ __launch_bounds__(256) void xg_mfma(
    const float* __restrict__ X,            // [M][K] fp32
    const unsigned short* __restrict__ WxT, // [N][K] bf16
    const float* __restrict__ bx, const float* __restrict__ bh,
    float* __restrict__ C) {                // [M][N] fp32
  __shared__ char sAB[16384] __attribute__((aligned(16)));
  char* sA = sAB;
  char* sB = sAB + 8192;
  const int tid = threadIdx.x;
  const int m0 = blockIdx.y * 128;
  const int n0 = blockIdx.x * 128;
  const int w = tid >> 6, l = tid & 63;
  const int wm = (w >> 1) * 64, wn = (w & 1) * 64;
  const int r2 = tid >> 1, kh = tid & 1;

  f32x4 acc[4][4];
#pragma unroll
  for (int i = 0; i < 4; ++i)
#pragma unroll
    for (int j = 0; j < 4; ++j) acc[i][j] = (f32x4){0.f, 0.f, 0.f, 0.f};

  for (int k0 = 0; k0 < Idim; k0 += 32) {
    const float* xa = &X[(size_t)(m0 + r2) * Idim + k0 + kh * 16];
    float4 a0 = *(const float4*)(xa + 0), a1 = *(const float4*)(xa + 4);
    float4 a2 = *(const float4*)(xa + 8), a3 = *(const float4*)(xa + 12);
    const char* wb = (const char*)&WxT[(size_t)(n0 + r2) * Idim + k0 + kh * 16];
    u32x4 b0 = *(const u32x4*)wb;
    u32x4 b1 = *(const u32x4*)(wb + 16);
    __syncthreads();
    u32x4 pa0 = {pack2(a0.x, a0.y), pack2(a0.z, a0.w),
                 pack2(a1.x, a1.y), pack2(a1.z, a1.w)};
    u32x4 pa1 = {pack2(a2.x, a2.y), pack2(a2.z, a2.w),
                 pack2(a3.x, a3.y), pack2(a3.z, a3.w)};
    const int sw = (r2 & 7) << 4;
    const int rb = r2 * 64 + kh * 32;
    *(u32x4*)(sA + ((rb + 0) ^ sw)) = pa0;
    *(u32x4*)(sA + ((rb + 16) ^ sw)) = pa1;
    *(u32x4*)(sB + ((rb + 0) ^ sw)) = b0;
    *(u32x4*)(sB + ((rb + 16) ^ sw)) = b1;
    __syncthreads();
    bf16x8 af[4], bf[4];
#pragma unroll
    for (int i = 0; i < 4; ++i) {
      int ra = wm + i * 16 + (l & 15);
      af[i] = *(const bf16x8*)(sA + ((ra * 64 + (l >> 4) * 16) ^ ((ra & 7) << 4)));
      int rn = wn + i * 16 + (l & 15);
      bf[i] = *(const bf16x8*)(sB + ((rn * 64 + (l >> 4) * 16) ^ ((rn & 7) << 4)));
    }
#pragma unroll
    for (int i = 0; i < 4; ++i)
#pragma unroll
      for (int j = 0; j < 4; ++j)
        acc[i][j] = __builtin_amdgcn_mfma_f32_16x16x32_bf16(af[i], bf[j],
                                                            acc[i][j], 0, 0, 0);
  }
  float bias[4];
#pragma unroll
  for (int j = 0; j < 4; ++j) {
    int cc = n0 + wn + j * 16 + (l & 15);
    bias[j] = bx[cc] + bh[cc];
  }
#pragma unroll
  for (int i = 0; i < 4; ++i) {
    int rbase = m0 + wm + i * 16 + (l >> 4) * 4;
#pragma unroll
    for (int j = 0; j < 4; ++j) {
      int cc = n0 + wn + j * 16 + (l & 15);
#pragma unroll
      for (int r = 0; r < 4; ++r)
        C[(size_t)(rbase + r) * Hdim + cc] = acc[i][j][r] + bias[j];
    }
  }
}

// ---------------- flag clear (agent stores -> MALL) --------------------------
__global__ void clear_flags(unsigned int* flags) {
  __hip_atomic_store(&flags[threadIdx.x], 0u, __ATOMIC_RELAXED,
                     __HIP_MEMORY_SCOPE_AGENT);
}

// ---------------- Phase 2: persistent MFMA scan ------------------------------
// flags: [c*64 + m*8 + w], 512 dwords. hbuf: [2 par][64 b][512 cp] dwords.
__global__ __launch_bounds__(512, 2) void rnn_scan(
    const unsigned short* __restrict__ WhT,  // [N=1024][K=1024] bf16
    float* __restrict__ out,                 // [B][T][H]: xproj in, h out
    float* __restrict__ hlast,               // [B][H]
    unsigned int* hbuf,                      // ws: 256 KB payload
    unsigned int* flags) {                   // ws: 512 dwords
  const int bid = blockIdx.x;
  const int c = bid & 7;   // cluster: batches c*8..+8
  const int m = bid >> 3;  // member: cols m*128..+128
  const int tid = threadIdx.x;
  const int w = tid >> 6;  // wave: k-slice w*128..+128; batch row w
  const int l = tid & 63;
  const int n0 = m * 128;

  __shared__ char smem[16384 + 33792] __attribute__((aligned(16)));
  char* const smh = smem;          // h tile [8 b][2048 B], XOR-swizzled
  char* const smp = smem + 16384;  // partials [8 w][8 nt][33][16 B]

  // B-frags: Wh[k=w*128..+128][cols n0..+128] = 32 x bf16x8 (unified reg file)
  bf16x8 bfrag[32];
  {
    const int kb = (w << 7) + ((l >> 4) << 3);
    const int col = n0 + (l & 15);
#pragma unroll
    for (int nt = 0; nt < 8; ++nt)
#pragma unroll
      for (int kt = 0; kt < 4; ++kt)
        bfrag[nt * 4 + kt] =
            *(const bf16x8*)&WhT[(size_t)(col + nt * 16) * 1024 + kb + kt * 32];
  }
#pragma unroll
  for (int i = 0; i < 32; ++i) asm volatile("" : "+v"(bfrag[i]));

  const int c0 = l * 2;  // col pair this thread finishes
  const int b_abs = c * 8 + w;
  const int nt0 = c0 >> 4;
  const int lane0 = ((w >> 2) << 4) | (c0 & 15);
  const int regb = (w & 3) * 4;
  const size_t orow = (size_t)b_abs * ((size_t)Tdim * Hdim) + n0 + c0;
  unsigned int* const myflag = &flags[c * 64 + m * 8 + w];
  const unsigned int* const pollf = &flags[c * 64 + l];

  float2 xp = *(const float2*)&out[orow];  // xproj t=0

  for (int t = 0; t < Tdim; ++t) {
    float sum0 = 0.f, sum1 = 0.f;
    if (t > 0) {
      // ---- compute from smh (staged at end of previous iteration) ----
      const int arow = l & 7;
      const int ab = arow * 2048 + (w << 8) + ((l >> 4) << 4);
      const int sw2 = arow << 4;
      bf16x8 af0 = *(const bf16x8*)(smh + ((ab + 0) ^ sw2));
      bf16x8 af1 = *(const bf16x8*)(smh + ((ab + 64) ^ sw2));
      bf16x8 af2 = *(const bf16x8*)(smh + ((ab + 128) ^ sw2));
      bf16x8 af3 = *(const bf16x8*)(smh + ((ab + 192) ^ sw2));
#pragma unroll
      for (int nt = 0; nt < 8; ++nt) {
        f32x4 a = {0.f, 0.f, 0.f, 0.f};
        a = __builtin_amdgcn_mfma_f32_16x16x32_bf16(af0, bfrag[nt * 4 + 0], a, 0, 0, 0);
        a = __builtin_amdgcn_mfma_f32_16x16x32_bf16(af1, bfrag[nt * 4 + 1], a, 0, 0, 0);
        a = __builtin_amdgcn_mfma_f32_16x16x32_bf16(af2, bfrag[nt * 4 + 2], a, 0, 0, 0);
        a = __builtin_amdgcn_mfma_f32_16x16x32_bf16(af3, bfrag[nt * 4 + 3], a, 0, 0, 0);
        if (l < 32)  // lanes 32-63 hold duplicate batch rows: discard
          *(f32x4*)(smp + (((w * 8 + nt) * 33 + l) << 4)) = a;
      }
      asm volatile("s_waitcnt lgkmcnt(0)" ::: "memory");
      __builtin_amdgcn_s_barrier();  // #P: partials visible
      asm volatile("" ::: "memory");
#pragma unroll
      for (int w8 = 0; w8 < 8; ++w8) {
        const char* p = smp + (((w8 * 8 + nt0) * 33 + lane0) << 4) + regb;
        sum0 += *(const float*)p;
        sum1 += *(const float*)(p + 16);
      }
    }
    float h0 = tanh_fast(xp.x + sum0);
    float h1 = tanh_fast(xp.y + sum1);
    if (t == Tdim - 1) {
      *(float2*)&out[orow + (size_t)t * Hdim] = make_float2(h0, h1);
      *(float2*)&hlast[(size_t)b_abs * Hdim + n0 + c0] = make_float2(h0, h1);
      break;
    }
    const int par = (t + 1) & 1;
    // ---- publish ONLY, drained (MALL ack ~500cy; queue is empty here) ----
    {
      unsigned int* pubp = hbuf + (size_t)par * 32768 + (size_t)b_abs * 512 +
                           m * 64 + l;
      unsigned int pv = pack2(h0, h1);
      asm volatile(
          "global_store_dword %0, %1, off sc0 sc1\n\ts_waitcnt vmcnt(0)"
          :: "v"(pubp), "v"(pv) : "memory");
    }
    // ---- per-wave flag: this wave's publishes proven MALL-visible ----
    if (l == 0) {
      unsigned int tv = (unsigned int)(t + 1);
      asm volatile("global_store_dword %0, %1, off sc0 sc1"
                   :: "v"(myflag), "v"(tv) : "memory");
    }
    // ---- off-critical-path HBM ops (IR; float across poll + stage) ----
    *(float2*)&out[orow + (size_t)t * Hdim] = make_float2(h0, h1);
    xp = *(const float2*)&out[orow + (size_t)(t + 1) * Hdim];
    // ---- wave7 polls the cluster's 64 per-wave flags (one 256B line) ----
    if (w == 7) {
      const unsigned int tgt = (unsigned int)(t + 1);
      for (;;) {
        unsigned int v;
        asm volatile(
            "global_load_dword %0, %1, off sc0 sc1\n\ts_waitcnt vmcnt(0)"
            : "=v"(v) : "v"(pollf) : "memory");
        if (__ballot(v >= tgt) == ~0ull) break;
        __builtin_amdgcn_s_sleep(1);
      }
    }
    __builtin_amdgcn_s_barrier();  // #C: flags observed
    asm volatile("" ::: "memory");
    // ---- stage tile for t+1: MALL loads only, self-drained ----
    {
      const char* srcp = (const char*)hbuf + (size_t)par * 131072 +
                         (size_t)b_abs * 2048 + l * 32;
      u32x4 d0, d1;
      asm volatile(
          "global_load_dwordx4 %0, %2, off sc0 sc1\n\t"
          "global_load_dwordx4 %1, %2, off offset:16 sc0 sc1\n\t"
          "s_waitcnt vmcnt(0)"
          : "=&v"(d0), "=&v"(d1) : "v"(srcp) : "memory");
      __builtin_amdgcn_sched_barrier(0);
      const int base = w * 2048 + l * 32;
      const int swz = w << 4;
      *(u32x4*)(smh + (base ^ swz)) = d0;
      *(u32x4*)(smh + ((base + 16) ^ swz)) = d1;
    }
    asm volatile("s_waitcnt lgkmcnt(0)" ::: "memory");
    __builtin_amdgcn_s_barrier();  // #D: tile staged
    asm volatile("" ::: "memory");
  }
}

extern "C" void kernel_launch(void* const* d_in, const int* in_sizes, int n_in,
                              void* d_out, int out_size, void* d_ws,
                              size_t ws_size, hipStream_t stream) {
  const float* x  = (const float*)d_in[0];
  const float* Wx = (const float*)d_in[1];
  const float* bx = (const float*)d_in[2];
  const float* Wh = (const float*)d_in[3];
  const float* bh = (const float*)d_in[4];
  float* out = (float*)d_out;
  float* hlast = out + (size_t)Bdim * Tdim * Hdim;
  unsigned int* flags = (unsigned int*)d_ws;                       // 2 KB
  unsigned int* hbuf = (unsigned int*)((char*)d_ws + 4096);        // 256 KB
  unsigned short* WxT = (unsigned short*)((char*)d_ws + 4096 + 262144);
  unsigned short* WhT = (unsigned short*)((char*)d_ws + 4096 + 262144 + 2097152);

  clear_flags<<<1, dim3(512), 0, stream>>>(flags);
  dim3 gt(32, 32);
  cvt_transpose<<<gt, dim3(256), 0, stream>>>(Wx, WxT);
  cvt_transpose<<<gt, dim3(256), 0, stream>>>(Wh, WhT);
  xg_mfma<<<dim3(Hdim / 128, Mdim / 128), dim3(256), 0, stream>>>(x, WxT, bx,
                                                                  bh, out);
  rnn_scan<<<dim3(64), dim3(512), 0, stream>>>(WhT, out, hlast, hbuf, flags);
}

// Round 15
// 1560.864 us; speedup vs baseline: 2.7728x; 1.2098x over previous
//
#include <hip/hip_runtime.h>

// RNN: B=64, T=512, I=1024, H=1024, fp32 in/out.
// Phase 0: transpose-convert Wx/Wh -> bf16 [N][K] in ws.
// Phase 1: xproj = x @ Wx + bx + bh (bf16 MFMA, fp32 accum) -> d_out.
// Phase 2: persistent MFMA scan, 64 blocks x 512 thr = 8 clusters x 8 members
//   -- the R7/R9-measured protocol (best: 1354us) with ONE fix:
//   wave7 (the poller) defers its HBM out-store/xp-load to after the stage
//   drain, so its poll loop's vmcnt(0) waits ONLY the poll load (R13/R14
//   lesson: an HBM ack inside the poll gates #C for the whole block).
//   Non-poller waves keep R7's exact [publish, out, xp] + vmcnt(2) queue.
//   Poll backoff s_sleep(2) -> s_sleep(1).

#define Bdim 64
#define Tdim 512
#define Idim 1024
#define Hdim 1024
#define Mdim (Bdim * Tdim)  // 32768

typedef __attribute__((ext_vector_type(8))) short bf16x8;
typedef __attribute__((ext_vector_type(4))) float f32x4;
typedef __attribute__((ext_vector_type(4))) unsigned int u32x4;

__device__ __forceinline__ float tanh_fast(float x) {
  float e = __expf(2.0f * x);
  return 1.0f - 2.0f / (e + 1.0f);
}
__device__ __forceinline__ unsigned int f2bf(float f) {
  unsigned int u = __float_as_uint(f);
  return (u + 0x7FFFu + ((u >> 16) & 1u)) >> 16;  // RNE
}
__device__ __forceinline__ unsigned int pack2(float lo, float hi) {
  return f2bf(lo) | (f2bf(hi) << 16);
}

// ---------------- Phase 0: fp32 [K][N] -> bf16 transposed [N][K] -------------
__global__ __launch_bounds__(256) void cvt_transpose(
    const float* __restrict__ src, unsigned short* __restrict__ dst) {
  __shared__ float t[32][33];
  const int bx = blockIdx.x * 32;
  const int by = blockIdx.y * 32;
  const int ty = threadIdx.x >> 3;
  const int tx = threadIdx.x & 7;
  float4 v = *(const float4*)&src[(size_t)(by + ty) * 1024 + bx + tx * 4];
  t[ty][tx * 4 + 0] = v.x; t[ty][tx * 4 + 1] = v.y;
  t[ty][tx * 4 + 2] = v.z; t[ty][tx * 4 + 3] = v.w;
  __syncthreads();
  ushort4 o;
  o.x = (unsigned short)f2bf(t[tx * 4 + 0][ty]);
  o.y = (unsigned short)f2bf(t[tx * 4 + 1][ty]);
  o.z = (unsigned short)f2bf(t[tx * 4 + 2][ty]);
  o.w = (unsigned short)f2bf(t[tx * 4 + 3][ty]);
  *(ushort4*)&dst[(size_t)(bx + ty) * 1024 + by + tx * 4] = o;
}

// ---------------- Phase 1: bf16 MFMA GEMM, 128x128 tile, BK=32 ---------------
__global__ __launch_bounds__(256) void xg_mfma(
    const float* __restrict__ X,            // [M][K] fp32
    const unsigned short* __restrict__ WxT, // [N][K] bf16
    const float* __restrict__ bx, const float* __restrict__ bh,
    float* __restrict__ C) {                // [M][N] fp32
  __shared__ char sAB[16384] __attribute__((aligned(16)));
  char* sA = sAB;
  char* sB = sAB + 8192;
  const int tid = threadIdx.x;
  const int m0 = blockIdx.y * 128;
  const int n0 = blockIdx.x * 128;
  const int w = tid >> 6, l = tid & 63;
  const int wm = (w >> 1) * 64, wn = (w & 1) * 64;
  const int r2 = tid >> 1, kh = tid & 1;

  f32x4 acc[4][4];
#pragma unroll
  for (int i = 0; i < 4; ++i)
#pragma unroll
    for (int j = 0; j < 4; ++j) acc[i][j] = (f32x4){0.f, 0.f, 0.f, 0.f};

  for (int k0 = 0; k0 < Idim; k0 += 32) {
    const float* xa = &X[(size_t)(m0 + r2) * Idim + k0 + kh * 16];
    float4 a0 = *(const float4*)(xa + 0), a1 = *(const float4*)(xa + 4);
    float4 a2 = *(const float4*)(xa + 8), a3 = *(const float4*)(xa + 12);
    const char* wb = (const char*)&WxT[(size_t)(n0 + r2) * Idim + k0 + kh * 16];
    u32x4 b0 = *(const u32x4*)wb;
    u32x4 b1 = *(const u32x4*)(wb + 16);
    __syncthreads();
    u32x4 pa0 = {pack2(a0.x, a0.y), pack2(a0.z, a0.w),
                 pack2(a1.x, a1.y), pack2(a1.z, a1.w)};
    u32x4 pa1 = {pack2(a2.x, a2.y), pack2(a2.z, a2.w),
                 pack2(a3.x, a3.y), pack2(a3.z, a3.w)};
    const int sw = (r2 & 7) << 4;
    const int rb = r2 * 64 + kh * 32;
    *(u32x4*)(sA + ((rb + 0) ^ sw)) = pa0;
    *(u32x4*)(sA + ((rb + 16) ^ sw)) = pa1;
    *(u32x4*)(sB + ((rb + 0) ^ sw)) = b0;
    *(u32x4*)(sB + ((rb + 16) ^ sw)) = b1;
    __syncthreads();
    bf16x8 af[4], bf[4];
#pragma unroll
    for (int i = 0; i < 4; ++i) {
      int ra = wm + i * 16 + (l & 15);
      af[i] = *(const bf16x8*)(sA + ((ra * 64 + (l >> 4) * 16) ^ ((ra & 7) << 4)));
      int rn = wn + i * 16 + (l & 15);
      bf[i] = *(const bf16x8*)(sB + ((rn * 64 + (l >> 4) * 16) ^ ((rn & 7) << 4)));
    }
#pragma unroll
    for (int i = 0; i < 4; ++i)
#pragma unroll
      for (int j = 0; j < 4; ++j)
        acc[i][j] = __builtin_amdgcn_mfma_f32_16x16x32_bf16(af[i], bf[j],
                                                            acc[i][j], 0, 0, 0);
  }
  float bias[4];
#pragma unroll
  for (int j = 0; j < 4; ++j) {
    int cc = n0 + wn + j * 16 + (l & 15);
    bias[j] = bx[cc] + bh[cc];
  }
#pragma unroll
  for (int i = 0; i < 4; ++i) {
    int rbase = m0 + wm + i * 16 + (l >> 4) * 4;
#pragma unroll
    for (int j = 0; j < 4; ++j) {
      int cc = n0 + wn + j * 16 + (l & 15);
#pragma unroll
      for (int r = 0; r < 4; ++r)
        C[(size_t)(rbase + r) * Hdim + cc] = acc[i][j][r] + bias[j];
    }
  }
}

// ---------------- flag clear (agent stores -> MALL) --------------------------
__global__ void clear_flags(unsigned int* flags) {
  __hip_atomic_store(&flags[threadIdx.x], 0u, __ATOMIC_RELAXED,
                     __HIP_MEMORY_SCOPE_AGENT);
}

// ---------------- Phase 2: persistent MFMA scan (R7 + clean-poll fix) --------
// flags: [c*32 + m], one 128B line per cluster. hbuf: [2 par][64 b][512 cp].
__global__ __launch_bounds__(512, 2) void rnn_scan(
    const unsigned short* __restrict__ WhT,  // [N=1024][K=1024] bf16
    float* __restrict__ out,                 // [B][T][H]: xproj in, h out
    float* __restrict__ hlast,               // [B][H]
    unsigned int* hbuf,                      // ws: 256 KB payload
    unsigned int* flags) {                   // ws: 256 dwords
  const int bid = blockIdx.x;
  const int c = bid & 7;   // cluster: batches c*8..+8
  const int m = bid >> 3;  // member: cols m*128..+128
  const int tid = threadIdx.x;
  const int w = tid >> 6;  // wave: k-slice w*128..+128; batch row w
  const int l = tid & 63;
  const int n0 = m * 128;

  __shared__ char smem[16384 + 33792] __attribute__((aligned(16)));
  char* const smh = smem;          // h tile [8 b][2048 B], XOR-swizzled
  char* const smp = smem + 16384;  // partials [8 w][8 nt][33][16 B]

  // B-frags: Wh[k=w*128..+128][cols n0..+128] = 32 x bf16x8 (unified reg file)
  bf16x8 bfrag[32];
  {
    const int kb = (w << 7) + ((l >> 4) << 3);
    const int col = n0 + (l & 15);
#pragma unroll
    for (int nt = 0; nt < 8; ++nt)
#pragma unroll
      for (int kt = 0; kt < 4; ++kt)
        bfrag[nt * 4 + kt] =
            *(const bf16x8*)&WhT[(size_t)(col + nt * 16) * 1024 + kb + kt * 32];
  }
#pragma unroll
  for (int i = 0; i < 32; ++i) asm volatile("" : "+v"(bfrag[i]));

  const int c0 = l * 2;  // col pair this thread finishes
  const int b_abs = c * 8 + w;
  const int nt0 = c0 >> 4;
  const int lane0 = ((w >> 2) << 4) | (c0 & 15);
  const int regb = (w & 3) * 4;
  const size_t orow = (size_t)b_abs * ((size_t)Tdim * Hdim) + n0 + c0;
  unsigned int* const myflag = &flags[c * 32 + m];
  const unsigned int* const pollf = &flags[c * 32 + (l & 7)];

  float2 xp = *(const float2*)&out[orow];  // xproj t=0

  for (int t = 0; t < Tdim; ++t) {
    float sum0 = 0.f, sum1 = 0.f;
    if (t > 0) {
      // ---- compute from smh (staged at end of previous iteration) ----
      const int arow = l & 7;
      const int ab = arow * 2048 + (w << 8) + ((l >> 4) << 4);
      const int sw2 = arow << 4;
      bf16x8 af0 = *(const bf16x8*)(smh + ((ab + 0) ^ sw2));
      bf16x8 af1 = *(const bf16x8*)(smh + ((ab + 64) ^ sw2));
      bf16x8 af2 = *(const bf16x8*)(smh + ((ab + 128) ^ sw2));
      bf16x8 af3 = *(const bf16x8*)(smh + ((ab + 192) ^ sw2));
#pragma unroll
      for (int nt = 0; nt < 8; ++nt) {
        f32x4 a = {0.f, 0.f, 0.f, 0.f};
        a = __builtin_amdgcn_mfma_f32_16x16x32_bf16(af0, bfrag[nt * 4 + 0], a, 0, 0, 0);
        a = __builtin_amdgcn_mfma_f32_16x16x32_bf16(af1, bfrag[nt * 4 + 1], a, 0, 0, 0);
        a = __builtin_amdgcn_mfma_f32_16x16x32_bf16(af2, bfrag[nt * 4 + 2], a, 0, 0, 0);
        a = __builtin_amdgcn_mfma_f32_16x16x32_bf16(af3, bfrag[nt * 4 + 3], a, 0, 0, 0);
        if (l < 32)  // lanes 32-63 hold duplicate batch rows: discard
          *(f32x4*)(smp + (((w * 8 + nt) * 33 + l) << 4)) = a;
      }
      asm volatile("s_waitcnt lgkmcnt(0)" ::: "memory");
      __builtin_amdgcn_s_barrier();  // #P: partials visible
      asm volatile("" ::: "memory");
#pragma unroll
      for (int w8 = 0; w8 < 8; ++w8) {
        const char* p = smp + (((w8 * 8 + nt0) * 33 + lane0) << 4) + regb;
        sum0 += *(const float*)p;
        sum1 += *(const float*)(p + 16);
      }
    }
    float h0 = tanh_fast(xp.x + sum0);
    float h1 = tanh_fast(xp.y + sum1);
    if (t == Tdim - 1) {
      *(float2*)&out[orow + (size_t)t * Hdim] = make_float2(h0, h1);
      *(float2*)&hlast[(size_t)b_abs * Hdim + n0 + c0] = make_float2(h0, h1);
      break;
    }
    const int par = (t + 1) & 1;
    const unsigned int tp1 = (unsigned int)(t + 1);
    // ---- publish; non-poller waves batch out+xp behind it (R7 queue) ----
    {
      unsigned int* pubp = hbuf + (size_t)par * 32768 + (size_t)b_abs * 512 +
                           m * 64 + l;
      unsigned int pv = pack2(h0, h1);
      asm volatile("global_store_dword %0, %1, off sc0 sc1"
                   :: "v"(pubp), "v"(pv) : "memory");
    }
    if (w != 7) {
      *(float2*)&out[orow + (size_t)t * Hdim] = make_float2(h0, h1);
      xp = *(const float2*)&out[orow + (size_t)(t + 1) * Hdim];
      // queue: [publish, out-store, xp-load] -> vmcnt(2) == publish acked
      asm volatile("s_waitcnt vmcnt(2)" ::: "memory");
    } else {
      // poller: queue holds ONLY the publish -> clean drain, clean poll
      asm volatile("s_waitcnt vmcnt(0)" ::: "memory");
    }
    __builtin_amdgcn_s_barrier();  // #B: all publishes acked at MALL
    asm volatile("" ::: "memory");
    if (tid == 0)
      __hip_atomic_store(myflag, tp1, __ATOMIC_RELAXED,
                         __HIP_MEMORY_SCOPE_AGENT);
    if (w == 7) {  // poll 8 member flags (one 128B line); nothing else in queue
      for (;;) {
        unsigned int v;
        asm volatile(
            "global_load_dword %0, %1, off sc0 sc1\n\ts_waitcnt vmcnt(0)"
            : "=v"(v) : "v"(pollf) : "memory");
        if (__ballot(v >= tp1) == ~0ull) break;
        __builtin_amdgcn_s_sleep(1);
      }
    }
    __builtin_amdgcn_s_barrier();  // #C: flags observed
    asm volatile("" ::: "memory");
    // ---- stage tile for t+1: MALL loads only, self-drained ----
    {
      const char* srcp = (const char*)hbuf + (size_t)par * 131072 +
                         (size_t)b_abs * 2048 + l * 32;
      u32x4 d0, d1;
      asm volatile(
          "global_load_dwordx4 %0, %2, off sc0 sc1\n\t"
          "global_load_dwordx4 %1, %2, off offset:16 sc0 sc1\n\t"
          "s_waitcnt vmcnt(0)"
          : "=&v"(d0), "=&v"(d1) : "v"(srcp) : "memory");
      __builtin_amdgcn_sched_barrier(0);
      const int base = w * 2048 + l * 32;
      const int swz = w << 4;
      *(u32x4*)(smh + (base ^ swz)) = d0;
      *(u32x4*)(smh + ((base + 16) ^ swz)) = d1;
    }
    // ---- poller's deferred HBM ops: fly under next step's compute ----
    if (w == 7) {
      *(float2*)&out[orow + (size_t)t * Hdim] = make_float2(h0, h1);
      xp = *(const float2*)&out[orow + (size_t)(t + 1) * Hdim];
    }
    asm volatile("s_waitcnt lgkmcnt(0)" ::: "memory");
    __builtin_amdgcn_s_barrier();  // #D: tile staged
    asm volatile("" ::: "memory");
  }
}

extern "C" void kernel_launch(void* const* d_in, const int* in_sizes, int n_in,
                              void* d_out, int out_size, void* d_ws,
                              size_t ws_size, hipStream_t stream) {
  const float* x  = (const float*)d_in[0];
  const float* Wx = (const float*)d_in[1];
  const float* bx = (const float*)d_in[2];
  const float* Wh = (const float*)d_in[3];
  const float* bh = (const float*)d_in[4];
  float* out = (float*)d_out;
  float* hlast = out + (size_t)Bdim * Tdim * Hdim;
  unsigned int* flags = (unsigned int*)d_ws;                       // 1 KB
  unsigned int* hbuf = (unsigned int*)((char*)d_ws + 4096);        // 256 KB
  unsigned short* WxT = (unsigned short*)((char*)d_ws + 4096 + 262144);
  unsigned short* WhT = (unsigned short*)((char*)d_ws + 4096 + 262144 + 2097152);

  clear_flags<<<1, dim3(256), 0, stream>>>(flags);
  dim3 gt(32, 32);
  cvt_transpose<<<gt, dim3(256), 0, stream>>>(Wx, WxT);
  cvt_transpose<<<gt, dim3(256), 0, stream>>>(Wh, WhT);
  xg_mfma<<<dim3(Hdim / 128, Mdim / 128), dim3(256), 0, stream>>>(x, WxT, bx,
                                                                  bh, out);
  rnn_scan<<<dim3(64), dim3(512), 0, stream>>>(WhT, out, hlast, hbuf, flags);
}